// Round 13
// baseline (505.209 us; speedup 1.0000x reference)
//
#include <hip/hip_runtime.h>

#define BN_EPS 1e-5f
#define BSH 8  // 256 dsts per bucket

typedef __attribute__((ext_vector_type(8))) short bf16x8;
typedef __attribute__((ext_vector_type(4))) float f32x4;

__device__ inline float bfhi(unsigned int v) { return __uint_as_float(v & 0xFFFF0000u); }
__device__ inline float bflo(unsigned int v) { return __uint_as_float(v << 16); }
__device__ inline unsigned short f2bf(float f) {
  unsigned int u = __float_as_uint(f);
  u += 0x7FFFu + ((u >> 16) & 1u);  // RNE
  return (unsigned short)(u >> 16);
}
__device__ inline unsigned int pack2bf(float lo, float hi) {
  return (unsigned int)f2bf(lo) | ((unsigned int)f2bf(hi) << 16);
}

// ---------------- binned CSR build ----------------
__global__ void k_bucket(const int* __restrict__ src, const int* __restrict__ dst,
                         int* __restrict__ gcur, uint2* __restrict__ sedge,
                         int NB, int CAP, int E) {
  __shared__ int lh[512], rb[512];
  int tid = threadIdx.x;
  for (int i = tid; i < NB; i += 256) lh[i] = 0;
  __syncthreads();
  int base = blockIdx.x * 8192;
  int lim = min(8192, E - base);
  for (int i = tid; i < lim; i += 256)
    atomicAdd(&lh[dst[base + i] >> BSH], 1);
  __syncthreads();
  for (int i = tid; i < NB; i += 256) {
    int c = lh[i];
    rb[i] = c ? atomicAdd(&gcur[i], c) : 0;
    lh[i] = 0;
  }
  __syncthreads();
  for (int i = tid; i < lim; i += 256) {
    int d = dst[base + i];
    int s = src[base + i];
    int b = d >> BSH;
    int pos = rb[b] + atomicAdd(&lh[b], 1);
    if (pos < CAP) {
      uint2 v; v.x = (unsigned int)s; v.y = (unsigned int)d;
      sedge[(size_t)b * CAP + pos] = v;
    }
  }
}

__global__ void k_csr1(const uint2* __restrict__ sedge, const int* __restrict__ gcur,
                       int* __restrict__ startv, int* __restrict__ cnt,
                       float* __restrict__ dinv, int CAP, int n) {
  int b = blockIdx.x, tid = threadIdx.x;
  __shared__ int h[256], sc[256];
  h[tid] = 0;
  __syncthreads();
  int cb = gcur[b]; if (cb > CAP) cb = CAP;
  const uint2* sd = sedge + (size_t)b * CAP;
  for (int i = tid; i < cb; i += 256) atomicAdd(&h[sd[i].y & 255], 1);
  __syncthreads();
  int v = h[tid];
  sc[tid] = v;
  __syncthreads();
  for (int o = 1; o < 256; o <<= 1) {
    int t = (tid >= o) ? sc[tid - o] : 0;
    __syncthreads();
    sc[tid] += t;
    __syncthreads();
  }
  int gd = (b << BSH) + tid;
  if (gd < n) {
    startv[gd] = b * CAP + (sc[tid] - v);
    cnt[gd] = v;
    dinv[gd] = rsqrtf((float)v + 1.0f);
  }
}

// elist entry: src (17 bits) | round(dinv[src]*32767) (15 bits)
__global__ void k_csr2(const uint2* __restrict__ sedge, const int* __restrict__ gcur,
                       const int* __restrict__ startv, const float* __restrict__ dinv,
                       unsigned int* __restrict__ elist, int CAP, int n) {
  int b = blockIdx.x, tid = threadIdx.x;
  __shared__ int cur[256];
  int gd = (b << BSH) + tid;
  cur[tid] = (gd < n) ? startv[gd] : 0;
  __syncthreads();
  int cb = gcur[b]; if (cb > CAP) cb = CAP;
  const uint2* sd = sedge + (size_t)b * CAP;
  for (int i = tid; i < cb; i += 256) {
    uint2 e = sd[i];
    int pos = atomicAdd(&cur[e.y & 255], 1);
    unsigned int u = (unsigned int)(dinv[e.x] * 32767.0f + 0.5f);
    elist[pos] = e.x | (u << 17);
  }
}

// ---------------- all input conversions in one kernel ----------------
__global__ void k_cvtall(const float* __restrict__ x, const float* __restrict__ W0,
                         const float* __restrict__ W1, const float* __restrict__ W2,
                         unsigned short* __restrict__ xb, unsigned short* __restrict__ Wt0,
                         unsigned short* __restrict__ Wt1, unsigned short* __restrict__ Wt2,
                         int n) {
  int t = blockIdx.x * blockDim.x + threadIdx.x;
  if (t < 4096) {                       // Wt0 [128][32] <- W0 [30][128]
    int nn = t >> 5, k = t & 31;
    Wt0[t] = f2bf(k < 30 ? W0[k * 128 + nn] : 0.f);
  } else if (t < 20480) {               // Wt1 [128][128] <- W1 [128][128]
    int i = t - 4096; int nn = i >> 7, k = i & 127;
    Wt1[i] = f2bf(W1[k * 128 + nn]);
  } else if (t < 36864) {               // Wt2
    int i = t - 20480; int nn = i >> 7, k = i & 127;
    Wt2[i] = f2bf(W2[k * 128 + nn]);
  } else {                              // xbf [n][32] <- x [n][30]
    int i = t - 36864;
    if (i < n * 32) {
      int row = i >> 5, c = i & 31;
      xb[i] = f2bf(c < 30 ? x[row * 30 + c] : 0.f);
    }
  }
}

// ---------------- layer-0 gather on x [n,32] bf16 (64 B rows) ----------------
__global__ void k_gather0(const unsigned int* __restrict__ elist, const int* __restrict__ start,
                          const int* __restrict__ cnt, const float* __restrict__ dinv,
                          const uint4* __restrict__ x4,  // [n,4] uint4 (row = 32 bf16)
                          unsigned int* __restrict__ G0, int n) {
  int lane = threadIdx.x & 63;
  int wv   = threadIdx.x >> 6;
  int grp  = lane >> 2;          // 0..15 edge slot
  int q4   = lane & 3;           // col chunk
  int row  = blockIdx.x * 4 + wv;
  bool active = row < n;

  float acc[8];
  float di = 0.f, dq = 0.f;
  int len = 0;
  const unsigned int* ep = elist;
  if (active) {
    di = dinv[row];
    dq = di * (1.0f / 32767.0f);
    len = cnt[row];
    ep = elist + start[row];
  }
  {
    float selfw = (grp == 0 && active) ? di * di : 0.f;
    uint4 hv = (grp == 0 && active) ? x4[(size_t)row * 4 + q4] : make_uint4(0, 0, 0, 0);
    acc[0] = bflo(hv.x) * selfw; acc[1] = bfhi(hv.x) * selfw;
    acc[2] = bflo(hv.y) * selfw; acc[3] = bfhi(hv.y) * selfw;
    acc[4] = bflo(hv.z) * selfw; acc[5] = bfhi(hv.z) * selfw;
    acc[6] = bflo(hv.w) * selfw; acc[7] = bfhi(hv.w) * selfw;
  }
  for (int j = 0; j < len; j += 16) {
    int jj = j + grp;
    unsigned int e = (jj < len) ? ep[jj] : 0u;   // e==0 -> w==0, harmless row-0 load
    uint4 v = x4[(size_t)(e & 0x1FFFFu) * 4 + q4];
    float w = (float)(e >> 17) * dq;
    acc[0] = fmaf(bflo(v.x), w, acc[0]); acc[1] = fmaf(bfhi(v.x), w, acc[1]);
    acc[2] = fmaf(bflo(v.y), w, acc[2]); acc[3] = fmaf(bfhi(v.y), w, acc[3]);
    acc[4] = fmaf(bflo(v.z), w, acc[4]); acc[5] = fmaf(bfhi(v.z), w, acc[5]);
    acc[6] = fmaf(bflo(v.w), w, acc[6]); acc[7] = fmaf(bfhi(v.w), w, acc[7]);
  }
#pragma unroll
  for (int k = 0; k < 8; ++k) {
    acc[k] += __shfl_xor(acc[k], 4);
    acc[k] += __shfl_xor(acc[k], 8);
    acc[k] += __shfl_xor(acc[k], 16);
    acc[k] += __shfl_xor(acc[k], 32);
  }
  if (grp == 0 && active) {
    uint4 o;
    o.x = pack2bf(acc[0], acc[1]);
    o.y = pack2bf(acc[2], acc[3]);
    o.z = pack2bf(acc[4], acc[5]);
    o.w = pack2bf(acc[6], acc[7]);
    ((uint4*)G0)[(size_t)row * 4 + q4] = o;  // 32 bf16 = 4 uint4 per row
  }
}

// ---------------- MFMA GEMM: optional fused BN on A; optional bias+stats epilogue ----------------
__global__ void k_gemm_mfma(const unsigned short* __restrict__ A,
                            const unsigned short* __restrict__ Wt,
                            const float* __restrict__ scsh, int doBN,
                            const float* __restrict__ bias, float* __restrict__ bnslab,
                            int doStats, unsigned short* __restrict__ C, int n, int Kp) {
  __shared__ float ssc[128], ssh[128];
  if (doBN) {
    if (threadIdx.x < 128) {
      ssc[threadIdx.x] = scsh[threadIdx.x];
      ssh[threadIdx.x] = scsh[128 + threadIdx.x];
    }
    __syncthreads();
  }
  int wave = threadIdx.x >> 6;
  int lane = threadIdx.x & 63;
  int m0 = blockIdx.x * 128 + wave * 32;  // always < Npad; no early return (stats barrier)
  int lm = lane & 15;
  int lq = lane >> 4;

  f32x4 acc[2][8] = {};
  const unsigned short* Arow0 = A + (size_t)(m0 + lm) * Kp + lq * 8;
  const unsigned short* Arow1 = Arow0 + (size_t)16 * Kp;
  const unsigned short* Bbase = Wt + (size_t)lm * Kp + lq * 8;

  for (int k0 = 0; k0 < Kp; k0 += 32) {
    uint4 ra0 = *(const uint4*)(Arow0 + k0);
    uint4 ra1 = *(const uint4*)(Arow1 + k0);
    bf16x8 a0, a1;
    if (doBN) {
      int cb = k0 + lq * 8;
      unsigned int w0 = pack2bf(fmaxf(fmaf(bflo(ra0.x), ssc[cb+0], ssh[cb+0]), 0.f),
                                fmaxf(fmaf(bfhi(ra0.x), ssc[cb+1], ssh[cb+1]), 0.f));
      unsigned int w1 = pack2bf(fmaxf(fmaf(bflo(ra0.y), ssc[cb+2], ssh[cb+2]), 0.f),
                                fmaxf(fmaf(bfhi(ra0.y), ssc[cb+3], ssh[cb+3]), 0.f));
      unsigned int w2 = pack2bf(fmaxf(fmaf(bflo(ra0.z), ssc[cb+4], ssh[cb+4]), 0.f),
                                fmaxf(fmaf(bfhi(ra0.z), ssc[cb+5], ssh[cb+5]), 0.f));
      unsigned int w3 = pack2bf(fmaxf(fmaf(bflo(ra0.w), ssc[cb+6], ssh[cb+6]), 0.f),
                                fmaxf(fmaf(bfhi(ra0.w), ssc[cb+7], ssh[cb+7]), 0.f));
      uint4 pa0 = make_uint4(w0, w1, w2, w3);
      a0 = *(bf16x8*)&pa0;
      unsigned int y0 = pack2bf(fmaxf(fmaf(bflo(ra1.x), ssc[cb+0], ssh[cb+0]), 0.f),
                                fmaxf(fmaf(bfhi(ra1.x), ssc[cb+1], ssh[cb+1]), 0.f));
      unsigned int y1 = pack2bf(fmaxf(fmaf(bflo(ra1.y), ssc[cb+2], ssh[cb+2]), 0.f),
                                fmaxf(fmaf(bfhi(ra1.y), ssc[cb+3], ssh[cb+3]), 0.f));
      unsigned int y2 = pack2bf(fmaxf(fmaf(bflo(ra1.z), ssc[cb+4], ssh[cb+4]), 0.f),
                                fmaxf(fmaf(bfhi(ra1.z), ssc[cb+5], ssh[cb+5]), 0.f));
      unsigned int y3 = pack2bf(fmaxf(fmaf(bflo(ra1.w), ssc[cb+6], ssh[cb+6]), 0.f),
                                fmaxf(fmaf(bfhi(ra1.w), ssc[cb+7], ssh[cb+7]), 0.f));
      uint4 pa1 = make_uint4(y0, y1, y2, y3);
      a1 = *(bf16x8*)&pa1;
    } else {
      a0 = *(bf16x8*)&ra0;
      a1 = *(bf16x8*)&ra1;
    }
#pragma unroll
    for (int t = 0; t < 8; ++t) {
      bf16x8 b = *(const bf16x8*)(Bbase + (size_t)t * 16 * Kp + k0);
      acc[0][t] = __builtin_amdgcn_mfma_f32_16x16x32_bf16(a0, b, acc[0][t], 0, 0, 0);
      acc[1][t] = __builtin_amdgcn_mfma_f32_16x16x32_bf16(a1, b, acc[1][t], 0, 0, 0);
    }
  }

#pragma unroll
  for (int h = 0; h < 2; ++h) {
    int rbase = m0 + h * 16 + lq * 4;
#pragma unroll
    for (int t = 0; t < 8; ++t) {
      int col = t * 16 + lm;
      float bv = doStats ? bias[col] : 0.f;
#pragma unroll
      for (int r = 0; r < 4; ++r) {
        int row = rbase + r;
        if (row < n) C[(size_t)row * 128 + col] = f2bf(acc[h][t][r] + bv);
      }
    }
  }

  if (doStats) {
    __shared__ float sms[4][256];
#pragma unroll
    for (int t = 0; t < 8; ++t) {
      int col = t * 16 + lm;
      float bv = bias[col];
      float s = 0.f, s2 = 0.f;
#pragma unroll
      for (int h = 0; h < 2; ++h) {
        int rbase = m0 + h * 16 + lq * 4;
#pragma unroll
        for (int r = 0; r < 4; ++r) {
          if (rbase + r < n) {
            float v = acc[h][t][r] + bv;
            s += v; s2 = fmaf(v, v, s2);
          }
        }
      }
      s  += __shfl_xor(s, 16);  s  += __shfl_xor(s, 32);
      s2 += __shfl_xor(s2, 16); s2 += __shfl_xor(s2, 32);
      if (lq == 0) { sms[wave][col] = s; sms[wave][128 + col] = s2; }
    }
    __syncthreads();
    int tid = threadIdx.x;
    int slab = (blockIdx.x & 63) * 256;
    float tot = sms[0][tid] + sms[1][tid] + sms[2][tid] + sms[3][tid];
    atomicAdd(&bnslab[slab + tid], tot);
  }
}

// ---------------- CSR gather (layers 1-2): XCD-parity column split ----------------
// 2x blocks; half = blockIdx&1 selects cols [half*64, half*64+64). With round-robin
// blockIdx%8 -> XCD, even/odd halves pin to disjoint XCD sets, halving per-XCD
// compulsory h traffic. 8 edge slots (grp=lane>>3) x 8 chunks (c=lane&7), 16-edge unroll.
__global__ void k_gather(const unsigned int* __restrict__ elist, const int* __restrict__ start,
                         const int* __restrict__ cnt, const float* __restrict__ dinv,
                         const uint4* __restrict__ h4,  // [n,16] uint4 (row = 128 bf16)
                         const float* __restrict__ bias, unsigned int* __restrict__ agg,
                         float* __restrict__ bnsumP, int n) {
  int lane = threadIdx.x & 63;
  int wv   = threadIdx.x >> 6;
  int half = blockIdx.x & 1;
  int blk  = blockIdx.x >> 1;
  int grp  = lane >> 3;          // 0..7 edge slot
  int c    = lane & 7;           // chunk within half-row
  int hc   = half * 8 + c;       // chunk index in full row
  int row  = blk * 4 + wv;
  bool active = row < n;

  float acc[8];
  float di = 0.f, dq = 0.f;
  int len = 0;
  const unsigned int* ep = elist;
  if (active) {
    di = dinv[row];
    dq = di * (1.0f / 32767.0f);
    len = cnt[row];
    ep = elist + start[row];
  }

  {
    float selfw = (grp == 0 && active) ? di * di : 0.f;
    float4 b0 = make_float4(0.f, 0.f, 0.f, 0.f), b1 = b0;
    if (grp == 0 && active) {
      b0 = ((const float4*)bias)[hc * 2];
      b1 = ((const float4*)bias)[hc * 2 + 1];
    }
    uint4 hv = (grp == 0 && active) ? h4[(size_t)row * 16 + hc] : make_uint4(0, 0, 0, 0);
    acc[0] = fmaf(bflo(hv.x), selfw, b0.x);
    acc[1] = fmaf(bfhi(hv.x), selfw, b0.y);
    acc[2] = fmaf(bflo(hv.y), selfw, b0.z);
    acc[3] = fmaf(bfhi(hv.y), selfw, b0.w);
    acc[4] = fmaf(bflo(hv.z), selfw, b1.x);
    acc[5] = fmaf(bfhi(hv.z), selfw, b1.y);
    acc[6] = fmaf(bflo(hv.w), selfw, b1.z);
    acc[7] = fmaf(bfhi(hv.w), selfw, b1.w);
  }

  int j = 0;
  for (; j + 16 <= len; j += 16) {
    unsigned int e0 = ep[j + grp];
    unsigned int e1 = ep[j + 8 + grp];
    uint4 v0 = h4[(size_t)(e0 & 0x1FFFFu) * 16 + hc];
    uint4 v1 = h4[(size_t)(e1 & 0x1FFFFu) * 16 + hc];
    float w0 = (float)(e0 >> 17) * dq;
    float w1 = (float)(e1 >> 17) * dq;
    acc[0] = fmaf(bflo(v0.x), w0, acc[0]); acc[1] = fmaf(bfhi(v0.x), w0, acc[1]);
    acc[2] = fmaf(bflo(v0.y), w0, acc[2]); acc[3] = fmaf(bfhi(v0.y), w0, acc[3]);
    acc[4] = fmaf(bflo(v0.z), w0, acc[4]); acc[5] = fmaf(bfhi(v0.z), w0, acc[5]);
    acc[6] = fmaf(bflo(v0.w), w0, acc[6]); acc[7] = fmaf(bfhi(v0.w), w0, acc[7]);
    acc[0] = fmaf(bflo(v1.x), w1, acc[0]); acc[1] = fmaf(bfhi(v1.x), w1, acc[1]);
    acc[2] = fmaf(bflo(v1.y), w1, acc[2]); acc[3] = fmaf(bfhi(v1.y), w1, acc[3]);
    acc[4] = fmaf(bflo(v1.z), w1, acc[4]); acc[5] = fmaf(bfhi(v1.z), w1, acc[5]);
    acc[6] = fmaf(bflo(v1.w), w1, acc[6]); acc[7] = fmaf(bfhi(v1.w), w1, acc[7]);
  }
  for (; j < len; j += 8) {
    int jj = j + grp;
    unsigned int e = (jj < len) ? ep[jj] : 0u;  // w==0, harmless row-0 load
    uint4 v = h4[(size_t)(e & 0x1FFFFu) * 16 + hc];
    float w = (float)(e >> 17) * dq;
    acc[0] = fmaf(bflo(v.x), w, acc[0]); acc[1] = fmaf(bfhi(v.x), w, acc[1]);
    acc[2] = fmaf(bflo(v.y), w, acc[2]); acc[3] = fmaf(bfhi(v.y), w, acc[3]);
    acc[4] = fmaf(bflo(v.z), w, acc[4]); acc[5] = fmaf(bfhi(v.z), w, acc[5]);
    acc[6] = fmaf(bflo(v.w), w, acc[6]); acc[7] = fmaf(bfhi(v.w), w, acc[7]);
  }

  // merge the 8 edge-groups (lane bits 3..5)
#pragma unroll
  for (int k = 0; k < 8; ++k) {
    acc[k] += __shfl_xor(acc[k], 8);
    acc[k] += __shfl_xor(acc[k], 16);
    acc[k] += __shfl_xor(acc[k], 32);
  }

  __shared__ float sm[2][4][64];
  if (grp == 0) {  // lanes 0..7 hold the merged half-row
    if (active) {
      uint4 o;
      o.x = pack2bf(acc[0], acc[1]);
      o.y = pack2bf(acc[2], acc[3]);
      o.z = pack2bf(acc[4], acc[5]);
      o.w = pack2bf(acc[6], acc[7]);
      ((uint4*)agg)[(size_t)row * 16 + hc] = o;
    }
#pragma unroll
    for (int k = 0; k < 8; ++k) {
      float a = acc[k];  // 0 for inactive rows
      sm[0][wv][c * 8 + k] = a;
      sm[1][wv][c * 8 + k] = a * a;
    }
  }
  __syncthreads();
  int tid = threadIdx.x;
  int slab = (blk & 63) * 256;
  if (tid < 64) {
    float s = sm[0][0][tid] + sm[0][1][tid] + sm[0][2][tid] + sm[0][3][tid];
    atomicAdd(&bnsumP[slab + half * 64 + tid], s);
  } else if (tid < 128) {
    int cc = tid - 64;
    float s2 = sm[1][0][cc] + sm[1][1][cc] + sm[1][2][cc] + sm[1][3][cc];
    atomicAdd(&bnsumP[slab + 128 + half * 64 + cc], s2);
  }
}

// ---------------- BN finalize: reduce 64 slabs + scale/shift (256 threads) ----------------
__global__ void k_bnfinal(const float* __restrict__ bnsumP, const float* __restrict__ gamma,
                          const float* __restrict__ beta, float* __restrict__ scsh, int n) {
  int tid = threadIdx.x;         // 256: tid<128 sums, tid>=128 sumsqs
  int c = tid & 127;
  int which = tid >> 7;
  float s = 0.f;
  for (int k = 0; k < 64; ++k) s += bnsumP[k * 256 + which * 128 + c];
  __shared__ float sh[256];
  sh[tid] = s;
  __syncthreads();
  if (tid < 128) {
    float invn = 1.0f / (float)n;
    float mu  = sh[tid] * invn;
    float ex2 = sh[128 + tid] * invn;
    float var = fmaxf(ex2 - mu * mu, 0.f);
    float sc = gamma[tid] * rsqrtf(var + BN_EPS);
    scsh[tid] = sc;
    scsh[128 + tid] = fmaf(-mu, sc, beta[tid]);
  }
}

// ---------------- fused mean-pool (BN+ReLU on bf16 agg) + head MLP ----------------
__global__ void k_poolhead(const unsigned int* __restrict__ aggd, const float* __restrict__ scsh,
                           const int* __restrict__ batch, const float* __restrict__ HW1,
                           const float* __restrict__ Hb1, const float* __restrict__ HW2,
                           const float* __restrict__ Hb2, float* __restrict__ out, int n) {
  int g = blockIdx.x;
  int wv = threadIdx.x >> 6, t = threadIdx.x & 63;
  int lo = 0, hi = n;
  while (lo < hi) { int mid = (lo + hi) >> 1; if (batch[mid] < g) lo = mid + 1; else hi = mid; }
  int s = lo;
  lo = 0; hi = n;
  int g1 = g + 1;
  while (lo < hi) { int mid = (lo + hi) >> 1; if (batch[mid] < g1) lo = mid + 1; else hi = mid; }
  int e = lo;

  float sc0 = scsh[2 * t], sc1 = scsh[2 * t + 1];
  float sh0 = scsh[128 + 2 * t], sh1 = scsh[128 + 2 * t + 1];
  float a0 = 0.f, a1 = 0.f;
  for (int i = s + wv; i < e; i += 4) {
    unsigned int u = aggd[(size_t)i * 64 + t];
    a0 += fmaxf(fmaf(bflo(u), sc0, sh0), 0.f);
    a1 += fmaxf(fmaf(bfhi(u), sc1, sh1), 0.f);
  }
  __shared__ float pp[4][128];
  pp[wv][2 * t] = a0;
  pp[wv][2 * t + 1] = a1;
  __syncthreads();
  if (wv == 0) {
    float inv = 1.0f / fmaxf((float)(e - s), 1.f);
    float p0 = (pp[0][2 * t] + pp[1][2 * t] + pp[2][2 * t] + pp[3][2 * t]) * inv;
    float p1 = (pp[0][2 * t + 1] + pp[1][2 * t + 1] + pp[2][2 * t + 1] + pp[3][2 * t + 1]) * inv;
    pp[0][2 * t] = p0;
    pp[0][2 * t + 1] = p1;
    float acc = Hb1[t];
    for (int k = 0; k < 128; ++k) acc = fmaf(pp[0][k], HW1[k * 64 + t], acc);
    float v = fmaxf(acc, 0.f) * HW2[t];
    for (int off = 32; off > 0; off >>= 1) v += __shfl_down(v, off);
    if (t == 0) out[g] = v + Hb2[0];
  }
}

extern "C" void kernel_launch(void* const* d_in, const int* in_sizes, int n_in,
                              void* d_out, int out_size, void* d_ws, size_t ws_size,
                              hipStream_t stream) {
  const int F_IN = 30, H = 128;
  const float* x   = (const float*)d_in[0];
  const int* eidx  = (const int*)d_in[1];
  const int* batch = (const int*)d_in[2];
  const int N = in_sizes[0] / F_IN;
  const int E = in_sizes[1] / 2;
  const int G = out_size;
  const int* srcp = eidx;
  const int* dstp = eidx + E;
  const float* HW1 = (const float*)d_in[15];
  const float* Hb1 = (const float*)d_in[16];
  const float* HW2 = (const float*)d_in[17];
  const float* Hb2 = (const float*)d_in[18];
  float* outp = (float*)d_out;

  const int Npad = (N + 127) & ~127;
  size_t nh = (size_t)Npad * H;
  const int NB = (N + 255) >> BSH;
  const int CAP = ((E / NB) * 3) / 2 + 128;
  const int NBpad = (NB + 63) & ~63;

  // workspace layout (bf16 unless noted)
  unsigned short* bufH = (unsigned short*)d_ws;      // Npad*128 (gemm out h)
  unsigned short* bufX = bufH + nh;                  // Npad*128 (agg; sedge staging aliases)
  unsigned short* xbf  = bufX + nh;                  // Npad*32 (x0 bf16)
  unsigned short* G0   = xbf + (size_t)Npad * 32;    // Npad*32 (layer-0 gather out)
  float* dinv = (float*)(G0 + (size_t)Npad * 32);    // N (f32)
  int*   cnt    = (int*)(dinv + N);                  // N
  int*   startv = cnt + N;                           // N
  int*   gcur   = startv + N;                        // NBpad  [zeroed]
  float* bnsumP = (float*)(gcur + NBpad);            // 3*64*256 [zeroed]
  float* scsh   = bnsumP + 3 * 64 * 256;             // 256
  unsigned short* Wt0 = (unsigned short*)(scsh + 256);       // 128*32
  unsigned short* Wt1 = Wt0 + 128 * 32;                      // 128*128
  unsigned short* Wt2 = Wt1 + 128 * 128;                     // 128*128
  unsigned int* elist = (unsigned int*)(Wt2 + 128 * 128 + 64);  // NB*CAP (4B)
  uint2* sedge = (uint2*)bufX;  // staging aliases agg buffer (dead until L0 gemm writes it)

  hipMemsetAsync(gcur, 0, ((size_t)NBpad + 3 * 64 * 256) * sizeof(int), stream);

  // ---- binned CSR build (reused by all 3 layers) ----
  k_bucket<<<(E + 8191) / 8192, 256, 0, stream>>>(srcp, dstp, gcur, sedge, NB, CAP, E);
  k_csr1<<<NB, 256, 0, stream>>>(sedge, gcur, startv, cnt, dinv, CAP, N);
  k_csr2<<<NB, 256, 0, stream>>>(sedge, gcur, startv, dinv, elist, CAP, N);

  // ---- conversions ----
  k_cvtall<<<(36864 + N * 32 + 255) / 256, 256, 0, stream>>>(
      x, (const float*)d_in[3], (const float*)d_in[7], (const float*)d_in[11],
      xbf, Wt0, Wt1, Wt2, N);

  const float* b0  = (const float*)d_in[4];
  const float* gm0 = (const float*)d_in[5];
  const float* bt0 = (const float*)d_in[6];

  // ---- layer 0 (swapped): gather on x (64 B rows), then gemm with bias+stats ----
  k_gather0<<<(N + 3) / 4, 256, 0, stream>>>(elist, startv, cnt, dinv,
                                             (const uint4*)xbf, (unsigned int*)G0, N);
  k_gemm_mfma<<<Npad / 128, 256, 0, stream>>>(G0, Wt0, scsh, 0, b0, bnsumP, 1,
                                              bufX, N, 32);
  k_bnfinal<<<1, 256, 0, stream>>>(bnsumP, gm0, bt0, scsh, N);

  // ---- layers 1,2: gemm (fused BN-apply) -> column-split gather (bias+stats) ----
  const unsigned short* Wts[3] = {nullptr, Wt1, Wt2};
  for (int l = 1; l < 3; ++l) {
    const float* b  = (const float*)d_in[4 + l * 4];
    const float* gm = (const float*)d_in[5 + l * 4];
    const float* bt = (const float*)d_in[6 + l * 4];
    float* bnslab = bnsumP + (size_t)l * 64 * 256;

    k_gemm_mfma<<<Npad / 128, 256, 0, stream>>>(bufX, Wts[l], scsh, 1, nullptr, nullptr, 0,
                                                bufH, N, 128);
    k_gather<<<2 * ((N + 3) / 4), 256, 0, stream>>>(elist, startv, cnt, dinv,
                                                    (const uint4*)bufH, b,
                                                    (unsigned int*)bufX, bnslab, N);
    k_bnfinal<<<1, 256, 0, stream>>>(bnslab, gm, bt, scsh, N);
  }

  // fused pool (layer-2 BN+ReLU) + head
  k_poolhead<<<G, 256, 0, stream>>>((const unsigned int*)bufX, scsh, batch,
                                    HW1, Hb1, HW2, Hb2, outp, N);
}

// Round 14
// 457.415 us; speedup vs baseline: 1.1045x; 1.1045x over previous
//
#include <hip/hip_runtime.h>

#define BN_EPS 1e-5f
#define BSH 8  // 256 dsts per bucket

typedef __attribute__((ext_vector_type(8))) short bf16x8;
typedef __attribute__((ext_vector_type(4))) float f32x4;

__device__ inline float bfhi(unsigned int v) { return __uint_as_float(v & 0xFFFF0000u); }
__device__ inline float bflo(unsigned int v) { return __uint_as_float(v << 16); }
__device__ inline unsigned short f2bf(float f) {
  unsigned int u = __float_as_uint(f);
  u += 0x7FFFu + ((u >> 16) & 1u);  // RNE
  return (unsigned short)(u >> 16);
}
__device__ inline unsigned int pack2bf(float lo, float hi) {
  return (unsigned int)f2bf(lo) | ((unsigned int)f2bf(hi) << 16);
}

// ---------------- binned CSR build ----------------
__global__ void k_bucket(const int* __restrict__ src, const int* __restrict__ dst,
                         int* __restrict__ gcur, uint2* __restrict__ sedge,
                         int NB, int CAP, int E) {
  __shared__ int lh[512], rb[512];
  int tid = threadIdx.x;
  for (int i = tid; i < NB; i += 256) lh[i] = 0;
  __syncthreads();
  int base = blockIdx.x * 8192;
  int lim = min(8192, E - base);
  for (int i = tid; i < lim; i += 256)
    atomicAdd(&lh[dst[base + i] >> BSH], 1);
  __syncthreads();
  for (int i = tid; i < NB; i += 256) {
    int c = lh[i];
    rb[i] = c ? atomicAdd(&gcur[i], c) : 0;
    lh[i] = 0;
  }
  __syncthreads();
  for (int i = tid; i < lim; i += 256) {
    int d = dst[base + i];
    int s = src[base + i];
    int b = d >> BSH;
    int pos = rb[b] + atomicAdd(&lh[b], 1);
    if (pos < CAP) {
      uint2 v; v.x = (unsigned int)s; v.y = (unsigned int)d;
      sedge[(size_t)b * CAP + pos] = v;
    }
  }
}

__global__ void k_csr1(const uint2* __restrict__ sedge, const int* __restrict__ gcur,
                       int* __restrict__ startv, int* __restrict__ cnt,
                       float* __restrict__ dinv, int CAP, int n) {
  int b = blockIdx.x, tid = threadIdx.x;
  __shared__ int h[256], sc[256];
  h[tid] = 0;
  __syncthreads();
  int cb = gcur[b]; if (cb > CAP) cb = CAP;
  const uint2* sd = sedge + (size_t)b * CAP;
  for (int i = tid; i < cb; i += 256) atomicAdd(&h[sd[i].y & 255], 1);
  __syncthreads();
  int v = h[tid];
  sc[tid] = v;
  __syncthreads();
  for (int o = 1; o < 256; o <<= 1) {
    int t = (tid >= o) ? sc[tid - o] : 0;
    __syncthreads();
    sc[tid] += t;
    __syncthreads();
  }
  int gd = (b << BSH) + tid;
  if (gd < n) {
    startv[gd] = b * CAP + (sc[tid] - v);
    cnt[gd] = v;
    dinv[gd] = rsqrtf((float)v + 1.0f);
  }
}

// elist entry: src (17 bits) | round(dinv[src]*32767) (15 bits)
__global__ void k_csr2(const uint2* __restrict__ sedge, const int* __restrict__ gcur,
                       const int* __restrict__ startv, const float* __restrict__ dinv,
                       unsigned int* __restrict__ elist, int CAP, int n) {
  int b = blockIdx.x, tid = threadIdx.x;
  __shared__ int cur[256];
  int gd = (b << BSH) + tid;
  cur[tid] = (gd < n) ? startv[gd] : 0;
  __syncthreads();
  int cb = gcur[b]; if (cb > CAP) cb = CAP;
  const uint2* sd = sedge + (size_t)b * CAP;
  for (int i = tid; i < cb; i += 256) {
    uint2 e = sd[i];
    int pos = atomicAdd(&cur[e.y & 255], 1);
    unsigned int u = (unsigned int)(dinv[e.x] * 32767.0f + 0.5f);
    elist[pos] = e.x | (u << 17);
  }
}

// ---------------- all input conversions in one kernel ----------------
__global__ void k_cvtall(const float* __restrict__ x, const float* __restrict__ W0,
                         const float* __restrict__ W1, const float* __restrict__ W2,
                         unsigned short* __restrict__ xb, unsigned short* __restrict__ Wt0,
                         unsigned short* __restrict__ Wt1, unsigned short* __restrict__ Wt2,
                         int n) {
  int t = blockIdx.x * blockDim.x + threadIdx.x;
  if (t < 4096) {                       // Wt0 [128][32] <- W0 [30][128]
    int nn = t >> 5, k = t & 31;
    Wt0[t] = f2bf(k < 30 ? W0[k * 128 + nn] : 0.f);
  } else if (t < 20480) {               // Wt1 [128][128] <- W1 [128][128]
    int i = t - 4096; int nn = i >> 7, k = i & 127;
    Wt1[i] = f2bf(W1[k * 128 + nn]);
  } else if (t < 36864) {               // Wt2
    int i = t - 20480; int nn = i >> 7, k = i & 127;
    Wt2[i] = f2bf(W2[k * 128 + nn]);
  } else {                              // xbf [n][32] <- x [n][30]
    int i = t - 36864;
    if (i < n * 32) {
      int row = i >> 5, c = i & 31;
      xb[i] = f2bf(c < 30 ? x[row * 30 + c] : 0.f);
    }
  }
}

// ---------------- layer-0 gather on x [n,32] bf16 (64 B rows) ----------------
__global__ void k_gather0(const unsigned int* __restrict__ elist, const int* __restrict__ start,
                          const int* __restrict__ cnt, const float* __restrict__ dinv,
                          const uint4* __restrict__ x4,  // [n,4] uint4 (row = 32 bf16)
                          unsigned int* __restrict__ G0, int n) {
  int lane = threadIdx.x & 63;
  int wv   = threadIdx.x >> 6;
  int grp  = lane >> 2;          // 0..15 edge slot
  int q4   = lane & 3;           // col chunk
  int row  = blockIdx.x * 4 + wv;
  bool active = row < n;

  float acc[8];
  float di = 0.f, dq = 0.f;
  int len = 0;
  const unsigned int* ep = elist;
  if (active) {
    di = dinv[row];
    dq = di * (1.0f / 32767.0f);
    len = cnt[row];
    ep = elist + start[row];
  }
  {
    float selfw = (grp == 0 && active) ? di * di : 0.f;
    uint4 hv = (grp == 0 && active) ? x4[(size_t)row * 4 + q4] : make_uint4(0, 0, 0, 0);
    acc[0] = bflo(hv.x) * selfw; acc[1] = bfhi(hv.x) * selfw;
    acc[2] = bflo(hv.y) * selfw; acc[3] = bfhi(hv.y) * selfw;
    acc[4] = bflo(hv.z) * selfw; acc[5] = bfhi(hv.z) * selfw;
    acc[6] = bflo(hv.w) * selfw; acc[7] = bfhi(hv.w) * selfw;
  }
  for (int j = 0; j < len; j += 16) {
    int jj = j + grp;
    unsigned int e = (jj < len) ? ep[jj] : 0u;   // e==0 -> w==0, harmless row-0 load
    uint4 v = x4[(size_t)(e & 0x1FFFFu) * 4 + q4];
    float w = (float)(e >> 17) * dq;
    acc[0] = fmaf(bflo(v.x), w, acc[0]); acc[1] = fmaf(bfhi(v.x), w, acc[1]);
    acc[2] = fmaf(bflo(v.y), w, acc[2]); acc[3] = fmaf(bfhi(v.y), w, acc[3]);
    acc[4] = fmaf(bflo(v.z), w, acc[4]); acc[5] = fmaf(bfhi(v.z), w, acc[5]);
    acc[6] = fmaf(bflo(v.w), w, acc[6]); acc[7] = fmaf(bfhi(v.w), w, acc[7]);
  }
#pragma unroll
  for (int k = 0; k < 8; ++k) {
    acc[k] += __shfl_xor(acc[k], 4);
    acc[k] += __shfl_xor(acc[k], 8);
    acc[k] += __shfl_xor(acc[k], 16);
    acc[k] += __shfl_xor(acc[k], 32);
  }
  if (grp == 0 && active) {
    uint4 o;
    o.x = pack2bf(acc[0], acc[1]);
    o.y = pack2bf(acc[2], acc[3]);
    o.z = pack2bf(acc[4], acc[5]);
    o.w = pack2bf(acc[6], acc[7]);
    ((uint4*)G0)[(size_t)row * 4 + q4] = o;  // 32 bf16 = 4 uint4 per row
  }
}

// ---------------- MFMA GEMM: optional fused BN on A; optional bias+stats epilogue ----------------
__global__ void k_gemm_mfma(const unsigned short* __restrict__ A,
                            const unsigned short* __restrict__ Wt,
                            const float* __restrict__ scsh, int doBN,
                            const float* __restrict__ bias, float* __restrict__ bnslab,
                            int doStats, unsigned short* __restrict__ C, int n, int Kp) {
  __shared__ float ssc[128], ssh[128];
  if (doBN) {
    if (threadIdx.x < 128) {
      ssc[threadIdx.x] = scsh[threadIdx.x];
      ssh[threadIdx.x] = scsh[128 + threadIdx.x];
    }
    __syncthreads();
  }
  int wave = threadIdx.x >> 6;
  int lane = threadIdx.x & 63;
  int m0 = blockIdx.x * 128 + wave * 32;  // always < Npad; no early return (stats barrier)
  int lm = lane & 15;
  int lq = lane >> 4;

  f32x4 acc[2][8] = {};
  const unsigned short* Arow0 = A + (size_t)(m0 + lm) * Kp + lq * 8;
  const unsigned short* Arow1 = Arow0 + (size_t)16 * Kp;
  const unsigned short* Bbase = Wt + (size_t)lm * Kp + lq * 8;

  for (int k0 = 0; k0 < Kp; k0 += 32) {
    uint4 ra0 = *(const uint4*)(Arow0 + k0);
    uint4 ra1 = *(const uint4*)(Arow1 + k0);
    bf16x8 a0, a1;
    if (doBN) {
      int cb = k0 + lq * 8;
      unsigned int w0 = pack2bf(fmaxf(fmaf(bflo(ra0.x), ssc[cb+0], ssh[cb+0]), 0.f),
                                fmaxf(fmaf(bfhi(ra0.x), ssc[cb+1], ssh[cb+1]), 0.f));
      unsigned int w1 = pack2bf(fmaxf(fmaf(bflo(ra0.y), ssc[cb+2], ssh[cb+2]), 0.f),
                                fmaxf(fmaf(bfhi(ra0.y), ssc[cb+3], ssh[cb+3]), 0.f));
      unsigned int w2 = pack2bf(fmaxf(fmaf(bflo(ra0.z), ssc[cb+4], ssh[cb+4]), 0.f),
                                fmaxf(fmaf(bfhi(ra0.z), ssc[cb+5], ssh[cb+5]), 0.f));
      unsigned int w3 = pack2bf(fmaxf(fmaf(bflo(ra0.w), ssc[cb+6], ssh[cb+6]), 0.f),
                                fmaxf(fmaf(bfhi(ra0.w), ssc[cb+7], ssh[cb+7]), 0.f));
      uint4 pa0 = make_uint4(w0, w1, w2, w3);
      a0 = *(bf16x8*)&pa0;
      unsigned int y0 = pack2bf(fmaxf(fmaf(bflo(ra1.x), ssc[cb+0], ssh[cb+0]), 0.f),
                                fmaxf(fmaf(bfhi(ra1.x), ssc[cb+1], ssh[cb+1]), 0.f));
      unsigned int y1 = pack2bf(fmaxf(fmaf(bflo(ra1.y), ssc[cb+2], ssh[cb+2]), 0.f),
                                fmaxf(fmaf(bfhi(ra1.y), ssc[cb+3], ssh[cb+3]), 0.f));
      unsigned int y2 = pack2bf(fmaxf(fmaf(bflo(ra1.z), ssc[cb+4], ssh[cb+4]), 0.f),
                                fmaxf(fmaf(bfhi(ra1.z), ssc[cb+5], ssh[cb+5]), 0.f));
      unsigned int y3 = pack2bf(fmaxf(fmaf(bflo(ra1.w), ssc[cb+6], ssh[cb+6]), 0.f),
                                fmaxf(fmaf(bfhi(ra1.w), ssc[cb+7], ssh[cb+7]), 0.f));
      uint4 pa1 = make_uint4(y0, y1, y2, y3);
      a1 = *(bf16x8*)&pa1;
    } else {
      a0 = *(bf16x8*)&ra0;
      a1 = *(bf16x8*)&ra1;
    }
#pragma unroll
    for (int t = 0; t < 8; ++t) {
      bf16x8 b = *(const bf16x8*)(Bbase + (size_t)t * 16 * Kp + k0);
      acc[0][t] = __builtin_amdgcn_mfma_f32_16x16x32_bf16(a0, b, acc[0][t], 0, 0, 0);
      acc[1][t] = __builtin_amdgcn_mfma_f32_16x16x32_bf16(a1, b, acc[1][t], 0, 0, 0);
    }
  }

#pragma unroll
  for (int h = 0; h < 2; ++h) {
    int rbase = m0 + h * 16 + lq * 4;
#pragma unroll
    for (int t = 0; t < 8; ++t) {
      int col = t * 16 + lm;
      float bv = doStats ? bias[col] : 0.f;
#pragma unroll
      for (int r = 0; r < 4; ++r) {
        int row = rbase + r;
        if (row < n) C[(size_t)row * 128 + col] = f2bf(acc[h][t][r] + bv);
      }
    }
  }

  if (doStats) {
    __shared__ float sms[4][256];
#pragma unroll
    for (int t = 0; t < 8; ++t) {
      int col = t * 16 + lm;
      float bv = bias[col];
      float s = 0.f, s2 = 0.f;
#pragma unroll
      for (int h = 0; h < 2; ++h) {
        int rbase = m0 + h * 16 + lq * 4;
#pragma unroll
        for (int r = 0; r < 4; ++r) {
          if (rbase + r < n) {
            float v = acc[h][t][r] + bv;
            s += v; s2 = fmaf(v, v, s2);
          }
        }
      }
      s  += __shfl_xor(s, 16);  s  += __shfl_xor(s, 32);
      s2 += __shfl_xor(s2, 16); s2 += __shfl_xor(s2, 32);
      if (lq == 0) { sms[wave][col] = s; sms[wave][128 + col] = s2; }
    }
    __syncthreads();
    int tid = threadIdx.x;
    int slab = (blockIdx.x & 63) * 256;
    float tot = sms[0][tid] + sms[1][tid] + sms[2][tid] + sms[3][tid];
    atomicAdd(&bnslab[slab + tid], tot);
  }
}

// ---------------- CSR gather (layers 1-2), wave-per-row, 8-edge loop (R12-proven) ----------------
__global__ void k_gather(const unsigned int* __restrict__ elist, const int* __restrict__ start,
                         const int* __restrict__ cnt, const float* __restrict__ dinv,
                         const uint4* __restrict__ h4,  // [n,16] uint4 (row = 128 bf16)
                         const float* __restrict__ bias, unsigned int* __restrict__ agg,
                         float* __restrict__ bnsumP, int n) {
  int lane = threadIdx.x & 63;
  int wv   = threadIdx.x >> 6;
  int grp  = lane >> 4;
  int c8   = lane & 15;
  int row  = blockIdx.x * 4 + wv;
  bool active = row < n;

  float acc[8];
  float di = 0.f, dq = 0.f;
  int len = 0;
  const unsigned int* ep = elist;

  if (active) {
    di = dinv[row];
    dq = di * (1.0f / 32767.0f);
    len = cnt[row];
    ep = elist + start[row];
  }

  {
    float selfw = (grp == 0 && active) ? di * di : 0.f;
    float4 b0 = make_float4(0.f, 0.f, 0.f, 0.f), b1 = b0;
    if (grp == 0 && active) {
      b0 = ((const float4*)bias)[c8 * 2];
      b1 = ((const float4*)bias)[c8 * 2 + 1];
    }
    uint4 hv = active ? h4[(size_t)row * 16 + c8] : make_uint4(0, 0, 0, 0);
    acc[0] = fmaf(bflo(hv.x), selfw, b0.x);
    acc[1] = fmaf(bfhi(hv.x), selfw, b0.y);
    acc[2] = fmaf(bflo(hv.y), selfw, b0.z);
    acc[3] = fmaf(bfhi(hv.y), selfw, b0.w);
    acc[4] = fmaf(bflo(hv.z), selfw, b1.x);
    acc[5] = fmaf(bfhi(hv.z), selfw, b1.y);
    acc[6] = fmaf(bflo(hv.w), selfw, b1.z);
    acc[7] = fmaf(bfhi(hv.w), selfw, b1.w);
  }

  int j = 0;
  for (; j + 8 <= len; j += 8) {
    unsigned int e0 = ep[j + grp];
    unsigned int e1 = ep[j + 4 + grp];
    uint4 v0 = h4[(size_t)(e0 & 0x1FFFFu) * 16 + c8];
    uint4 v1 = h4[(size_t)(e1 & 0x1FFFFu) * 16 + c8];
    float w0 = (float)(e0 >> 17) * dq;
    float w1 = (float)(e1 >> 17) * dq;
    acc[0] = fmaf(bflo(v0.x), w0, acc[0]); acc[1] = fmaf(bfhi(v0.x), w0, acc[1]);
    acc[2] = fmaf(bflo(v0.y), w0, acc[2]); acc[3] = fmaf(bfhi(v0.y), w0, acc[3]);
    acc[4] = fmaf(bflo(v0.z), w0, acc[4]); acc[5] = fmaf(bfhi(v0.z), w0, acc[5]);
    acc[6] = fmaf(bflo(v0.w), w0, acc[6]); acc[7] = fmaf(bfhi(v0.w), w0, acc[7]);
    acc[0] = fmaf(bflo(v1.x), w1, acc[0]); acc[1] = fmaf(bfhi(v1.x), w1, acc[1]);
    acc[2] = fmaf(bflo(v1.y), w1, acc[2]); acc[3] = fmaf(bfhi(v1.y), w1, acc[3]);
    acc[4] = fmaf(bflo(v1.z), w1, acc[4]); acc[5] = fmaf(bfhi(v1.z), w1, acc[5]);
    acc[6] = fmaf(bflo(v1.w), w1, acc[6]); acc[7] = fmaf(bfhi(v1.w), w1, acc[7]);
  }
  for (; j < len; j += 4) {
    int jj = j + grp;
    unsigned int e = (jj < len) ? ep[jj] : 0u;
    uint4 v = h4[(size_t)(e & 0x1FFFFu) * 16 + c8];
    float w = (float)(e >> 17) * dq;
    acc[0] = fmaf(bflo(v.x), w, acc[0]); acc[1] = fmaf(bfhi(v.x), w, acc[1]);
    acc[2] = fmaf(bflo(v.y), w, acc[2]); acc[3] = fmaf(bfhi(v.y), w, acc[3]);
    acc[4] = fmaf(bflo(v.z), w, acc[4]); acc[5] = fmaf(bfhi(v.z), w, acc[5]);
    acc[6] = fmaf(bflo(v.w), w, acc[6]); acc[7] = fmaf(bfhi(v.w), w, acc[7]);
  }

#pragma unroll
  for (int k = 0; k < 8; ++k) {
    acc[k] += __shfl_xor(acc[k], 16);
    acc[k] += __shfl_xor(acc[k], 32);
  }

  __shared__ float sm[2][4][128];
  if (lane < 16) {
    if (active) {
      uint4 o;
      o.x = pack2bf(acc[0], acc[1]);
      o.y = pack2bf(acc[2], acc[3]);
      o.z = pack2bf(acc[4], acc[5]);
      o.w = pack2bf(acc[6], acc[7]);
      ((uint4*)agg)[(size_t)row * 16 + c8] = o;  // 128 bf16 = 16 uint4 per row
    }
#pragma unroll
    for (int k = 0; k < 8; ++k) {
      float a = acc[k];
      sm[0][wv][c8 * 8 + k] = a;
      sm[1][wv][c8 * 8 + k] = a * a;
    }
  }
  __syncthreads();
  int tid = threadIdx.x;
  int slab = (blockIdx.x & 63) * 256;
  if (tid < 128) {
    float s = sm[0][0][tid] + sm[0][1][tid] + sm[0][2][tid] + sm[0][3][tid];
    atomicAdd(&bnsumP[slab + tid], s);
  } else {
    int c = tid - 128;
    float s = sm[1][0][c] + sm[1][1][c] + sm[1][2][c] + sm[1][3][c];
    atomicAdd(&bnsumP[slab + 128 + c], s);
  }
}

// ---------------- BN finalize: reduce 64 slabs + scale/shift (256 threads) ----------------
__global__ void k_bnfinal(const float* __restrict__ bnsumP, const float* __restrict__ gamma,
                          const float* __restrict__ beta, float* __restrict__ scsh, int n) {
  int tid = threadIdx.x;         // 256: tid<128 sums, tid>=128 sumsqs
  int c = tid & 127;
  int which = tid >> 7;
  float s = 0.f;
  for (int k = 0; k < 64; ++k) s += bnsumP[k * 256 + which * 128 + c];
  __shared__ float sh[256];
  sh[tid] = s;
  __syncthreads();
  if (tid < 128) {
    float invn = 1.0f / (float)n;
    float mu  = sh[tid] * invn;
    float ex2 = sh[128 + tid] * invn;
    float var = fmaxf(ex2 - mu * mu, 0.f);
    float sc = gamma[tid] * rsqrtf(var + BN_EPS);
    scsh[tid] = sc;
    scsh[128 + tid] = fmaf(-mu, sc, beta[tid]);
  }
}

// ---------------- fused mean-pool (BN+ReLU on bf16 agg) + head MLP ----------------
__global__ void k_poolhead(const unsigned int* __restrict__ aggd, const float* __restrict__ scsh,
                           const int* __restrict__ batch, const float* __restrict__ HW1,
                           const float* __restrict__ Hb1, const float* __restrict__ HW2,
                           const float* __restrict__ Hb2, float* __restrict__ out, int n) {
  int g = blockIdx.x;
  int wv = threadIdx.x >> 6, t = threadIdx.x & 63;
  int lo = 0, hi = n;
  while (lo < hi) { int mid = (lo + hi) >> 1; if (batch[mid] < g) lo = mid + 1; else hi = mid; }
  int s = lo;
  lo = 0; hi = n;
  int g1 = g + 1;
  while (lo < hi) { int mid = (lo + hi) >> 1; if (batch[mid] < g1) lo = mid + 1; else hi = mid; }
  int e = lo;

  float sc0 = scsh[2 * t], sc1 = scsh[2 * t + 1];
  float sh0 = scsh[128 + 2 * t], sh1 = scsh[128 + 2 * t + 1];
  float a0 = 0.f, a1 = 0.f;
  for (int i = s + wv; i < e; i += 4) {
    unsigned int u = aggd[(size_t)i * 64 + t];
    a0 += fmaxf(fmaf(bflo(u), sc0, sh0), 0.f);
    a1 += fmaxf(fmaf(bfhi(u), sc1, sh1), 0.f);
  }
  __shared__ float pp[4][128];
  pp[wv][2 * t] = a0;
  pp[wv][2 * t + 1] = a1;
  __syncthreads();
  if (wv == 0) {
    float inv = 1.0f / fmaxf((float)(e - s), 1.f);
    float p0 = (pp[0][2 * t] + pp[1][2 * t] + pp[2][2 * t] + pp[3][2 * t]) * inv;
    float p1 = (pp[0][2 * t + 1] + pp[1][2 * t + 1] + pp[2][2 * t + 1] + pp[3][2 * t + 1]) * inv;
    pp[0][2 * t] = p0;
    pp[0][2 * t + 1] = p1;
    float acc = Hb1[t];
    for (int k = 0; k < 128; ++k) acc = fmaf(pp[0][k], HW1[k * 64 + t], acc);
    float v = fmaxf(acc, 0.f) * HW2[t];
    for (int off = 32; off > 0; off >>= 1) v += __shfl_down(v, off);
    if (t == 0) out[g] = v + Hb2[0];
  }
}

extern "C" void kernel_launch(void* const* d_in, const int* in_sizes, int n_in,
                              void* d_out, int out_size, void* d_ws, size_t ws_size,
                              hipStream_t stream) {
  const int F_IN = 30, H = 128;
  const float* x   = (const float*)d_in[0];
  const int* eidx  = (const int*)d_in[1];
  const int* batch = (const int*)d_in[2];
  const int N = in_sizes[0] / F_IN;
  const int E = in_sizes[1] / 2;
  const int G = out_size;
  const int* srcp = eidx;
  const int* dstp = eidx + E;
  const float* HW1 = (const float*)d_in[15];
  const float* Hb1 = (const float*)d_in[16];
  const float* HW2 = (const float*)d_in[17];
  const float* Hb2 = (const float*)d_in[18];
  float* outp = (float*)d_out;

  const int Npad = (N + 127) & ~127;
  size_t nh = (size_t)Npad * H;
  const int NB = (N + 255) >> BSH;
  const int CAP = ((E / NB) * 3) / 2 + 128;
  const int NBpad = (NB + 63) & ~63;

  // workspace layout (bf16 unless noted)
  unsigned short* bufH = (unsigned short*)d_ws;      // Npad*128 (gemm out h)
  unsigned short* bufX = bufH + nh;                  // Npad*128 (agg; sedge staging aliases)
  unsigned short* xbf  = bufX + nh;                  // Npad*32 (x0 bf16)
  unsigned short* G0   = xbf + (size_t)Npad * 32;    // Npad*32 (layer-0 gather out)
  float* dinv = (float*)(G0 + (size_t)Npad * 32);    // N (f32)
  int*   cnt    = (int*)(dinv + N);                  // N
  int*   startv = cnt + N;                           // N
  int*   gcur   = startv + N;                        // NBpad  [zeroed]
  float* bnsumP = (float*)(gcur + NBpad);            // 3*64*256 [zeroed]
  float* scsh   = bnsumP + 3 * 64 * 256;             // 256
  unsigned short* Wt0 = (unsigned short*)(scsh + 256);       // 128*32
  unsigned short* Wt1 = Wt0 + 128 * 32;                      // 128*128
  unsigned short* Wt2 = Wt1 + 128 * 128;                     // 128*128
  unsigned int* elist = (unsigned int*)(Wt2 + 128 * 128 + 64);  // NB*CAP (4B)
  uint2* sedge = (uint2*)bufX;  // staging aliases agg buffer (dead until L0 gemm writes it)

  hipMemsetAsync(gcur, 0, ((size_t)NBpad + 3 * 64 * 256) * sizeof(int), stream);

  // ---- binned CSR build (reused by all 3 layers) ----
  k_bucket<<<(E + 8191) / 8192, 256, 0, stream>>>(srcp, dstp, gcur, sedge, NB, CAP, E);
  k_csr1<<<NB, 256, 0, stream>>>(sedge, gcur, startv, cnt, dinv, CAP, N);
  k_csr2<<<NB, 256, 0, stream>>>(sedge, gcur, startv, dinv, elist, CAP, N);

  // ---- conversions ----
  k_cvtall<<<(36864 + N * 32 + 255) / 256, 256, 0, stream>>>(
      x, (const float*)d_in[3], (const float*)d_in[7], (const float*)d_in[11],
      xbf, Wt0, Wt1, Wt2, N);

  const float* b0  = (const float*)d_in[4];
  const float* gm0 = (const float*)d_in[5];
  const float* bt0 = (const float*)d_in[6];

  // ---- layer 0 (swapped): gather on x (64 B rows), then gemm with bias+stats ----
  k_gather0<<<(N + 3) / 4, 256, 0, stream>>>(elist, startv, cnt, dinv,
                                             (const uint4*)xbf, (unsigned int*)G0, N);
  k_gemm_mfma<<<Npad / 128, 256, 0, stream>>>(G0, Wt0, scsh, 0, b0, bnsumP, 1,
                                              bufX, N, 32);
  k_bnfinal<<<1, 256, 0, stream>>>(bnsumP, gm0, bt0, scsh, N);

  // ---- layers 1,2: gemm (fused BN-apply) -> gather (bias+stats) ----
  const unsigned short* Wts[3] = {nullptr, Wt1, Wt2};
  for (int l = 1; l < 3; ++l) {
    const float* b  = (const float*)d_in[4 + l * 4];
    const float* gm = (const float*)d_in[5 + l * 4];
    const float* bt = (const float*)d_in[6 + l * 4];
    float* bnslab = bnsumP + (size_t)l * 64 * 256;

    k_gemm_mfma<<<Npad / 128, 256, 0, stream>>>(bufX, Wts[l], scsh, 1, nullptr, nullptr, 0,
                                                bufH, N, 128);
    k_gather<<<(N + 3) / 4, 256, 0, stream>>>(elist, startv, cnt, dinv,
                                              (const uint4*)bufH, b,
                                              (unsigned int*)bufX, bnslab, N);
    k_bnfinal<<<1, 256, 0, stream>>>(bnslab, gm, bt, scsh, N);
  }

  // fused pool (layer-2 BN+ReLU) + head
  k_poolhead<<<G, 256, 0, stream>>>((const unsigned int*)bufX, scsh, batch,
                                    HW1, Hb1, HW2, Hb2, outp, N);
}